// Round 6
// baseline (850.395 us; speedup 1.0000x reference)
//
#include <hip/hip_runtime.h>
#include <hip/hip_bf16.h>
#include <math.h>

// Problem constants (fixed by the reference)
#define D_MODEL 2048
#define NHEAD   16
#define DK      128
#define SEQ     2048
#define BATCH   2
#define MROWS   (BATCH*SEQ)   // 4096 rows of (b,s)

typedef __attribute__((ext_vector_type(8))) short short8;
typedef __attribute__((ext_vector_type(4))) short shortx4;
typedef __attribute__((ext_vector_type(4))) float f32x4;

static __device__ __forceinline__ short f2bf(float v) {
    union { __hip_bfloat16 b; short s; } u;
    u.b = __float2bfloat16(v);
    return u.s;
}
static __device__ __forceinline__ float bf2f(short s) {
    union { short s; __hip_bfloat16 b; } u;
    u.s = s;
    return __bfloat162float(u.b);
}

// ---------------------------------------------------------------------------
// bf16x3 split-precision MFMA GEMM: C[M,N] = A[M,K] * W[N,K]^T  (fp32 in/out)
// 128x128 block tile, BK=32, 4 waves each owning a 64x64 sub-tile.
// Fragment layouts (HW-verified, learn_hip m89/m91/m92):
//   A/B: lane l reads 8 contiguous bf16 at row (l&15), k-offset (l>>4)*8
//   C/D: col = lane&15, row = (lane>>4)*4 + reg
// ---------------------------------------------------------------------------
#define GBM 128
#define GBN 128
#define GBK 32
#define LDKG 40   // shorts per LDS row: 32 data + 8 pad (80 B, keeps 16B align)

__global__ __launch_bounds__(256, 2) void gemm_nt_mfma(const float* __restrict__ A,
                                                       const float* __restrict__ W,
                                                       float* __restrict__ C,
                                                       int M, int N, int K)
{
    __shared__ __align__(16) short Ah[GBM][LDKG];
    __shared__ __align__(16) short Al[GBM][LDKG];
    __shared__ __align__(16) short Bh[GBN][LDKG];
    __shared__ __align__(16) short Bl[GBN][LDKG];

    const int tid  = threadIdx.x;
    const int lane = tid & 63;
    const int w    = tid >> 6;
    const int wm   = (w & 1) * 64;
    const int wn   = (w >> 1) * 64;
    const int l16  = lane & 15;
    const int kb   = (lane >> 4) * 8;

    const size_t row0 = (size_t)blockIdx.y * GBM;
    const size_t col0 = (size_t)blockIdx.x * GBN;

    const int sr0 = tid >> 2;
    const int sr1 = sr0 + 64;
    const int skc = (tid & 3) * 8;

    f32x4 acc[4][4];
#pragma unroll
    for (int i = 0; i < 4; ++i)
#pragma unroll
        for (int j = 0; j < 4; ++j) acc[i][j] = (f32x4)0.0f;

    float4 pa0a = *(const float4*)(A + (row0 + sr0) * K + skc);
    float4 pa0b = *(const float4*)(A + (row0 + sr0) * K + skc + 4);
    float4 pa1a = *(const float4*)(A + (row0 + sr1) * K + skc);
    float4 pa1b = *(const float4*)(A + (row0 + sr1) * K + skc + 4);
    float4 pw0a = *(const float4*)(W + (col0 + sr0) * K + skc);
    float4 pw0b = *(const float4*)(W + (col0 + sr0) * K + skc + 4);
    float4 pw1a = *(const float4*)(W + (col0 + sr1) * K + skc);
    float4 pw1b = *(const float4*)(W + (col0 + sr1) * K + skc + 4);

    for (int kt = 0; kt < K; kt += GBK) {
        {
            float f[8]; short8 h, l;
#define CVT8(va, vb)                                                        \
            f[0]=va.x; f[1]=va.y; f[2]=va.z; f[3]=va.w;                     \
            f[4]=vb.x; f[5]=vb.y; f[6]=vb.z; f[7]=vb.w;                     \
            _Pragma("unroll")                                               \
            for (int j = 0; j < 8; ++j) {                                   \
                short hb = f2bf(f[j]); h[j] = hb; l[j] = f2bf(f[j] - bf2f(hb)); \
            }
            CVT8(pa0a, pa0b)
            *(short8*)&Ah[sr0][skc] = h;  *(short8*)&Al[sr0][skc] = l;
            CVT8(pa1a, pa1b)
            *(short8*)&Ah[sr1][skc] = h;  *(short8*)&Al[sr1][skc] = l;
            CVT8(pw0a, pw0b)
            *(short8*)&Bh[sr0][skc] = h;  *(short8*)&Bl[sr0][skc] = l;
            CVT8(pw1a, pw1b)
            *(short8*)&Bh[sr1][skc] = h;  *(short8*)&Bl[sr1][skc] = l;
#undef CVT8
        }
        __syncthreads();

        if (kt + GBK < K) {
            const int kn = kt + GBK;
            pa0a = *(const float4*)(A + (row0 + sr0) * K + kn + skc);
            pa0b = *(const float4*)(A + (row0 + sr0) * K + kn + skc + 4);
            pa1a = *(const float4*)(A + (row0 + sr1) * K + kn + skc);
            pa1b = *(const float4*)(A + (row0 + sr1) * K + kn + skc + 4);
            pw0a = *(const float4*)(W + (col0 + sr0) * K + kn + skc);
            pw0b = *(const float4*)(W + (col0 + sr0) * K + kn + skc + 4);
            pw1a = *(const float4*)(W + (col0 + sr1) * K + kn + skc);
            pw1b = *(const float4*)(W + (col0 + sr1) * K + kn + skc + 4);
        }

        short8 bh[4], bl[4];
#pragma unroll
        for (int fn = 0; fn < 4; ++fn) {
            bh[fn] = *(const short8*)&Bh[wn + fn * 16 + l16][kb];
            bl[fn] = *(const short8*)&Bl[wn + fn * 16 + l16][kb];
        }
#pragma unroll
        for (int fm = 0; fm < 4; ++fm) {
            const short8 ah = *(const short8*)&Ah[wm + fm * 16 + l16][kb];
            const short8 al = *(const short8*)&Al[wm + fm * 16 + l16][kb];
#pragma unroll
            for (int fn = 0; fn < 4; ++fn) {
                acc[fm][fn] = __builtin_amdgcn_mfma_f32_16x16x32_bf16(ah, bh[fn], acc[fm][fn], 0, 0, 0);
                acc[fm][fn] = __builtin_amdgcn_mfma_f32_16x16x32_bf16(ah, bl[fn], acc[fm][fn], 0, 0, 0);
                acc[fm][fn] = __builtin_amdgcn_mfma_f32_16x16x32_bf16(al, bh[fn], acc[fm][fn], 0, 0, 0);
            }
        }
        __syncthreads();
    }

#pragma unroll
    for (int fm = 0; fm < 4; ++fm) {
#pragma unroll
        for (int j = 0; j < 4; ++j) {
            const size_t r = row0 + wm + fm * 16 + (lane >> 4) * 4 + j;
#pragma unroll
            for (int fn = 0; fn < 4; ++fn)
                C[r * N + col0 + wn + fn * 16 + l16] = acc[fm][fn][j];
        }
    }
}

// ---------------------------------------------------------------------------
// RoPE (in-place on q and k). inv_freq = 10000^(-2j/128) computed in DOUBLE
// (6e-8 rel err vs ~1e-6 for __expf -> ~5x less angle noise vs reference).
// ---------------------------------------------------------------------------
__global__ __launch_bounds__(256) void rope_kernel(float* __restrict__ q,
                                                   float* __restrict__ k,
                                                   const int* __restrict__ pos)
{
    const int idx = blockIdx.x * 256 + threadIdx.x;
    if (idx >= MROWS * 1024) return;
    const int pair = idx & 1023;        // h*64 + j
    const int row  = idx >> 10;         // b*SEQ + s
    const int s    = row & (SEQ - 1);
    const int j    = pair & 63;

    const float inv_freq = (float)pow(10000.0, -(double)(2 * j) / 128.0);
    const float ang = (float)pos[s] * inv_freq;
    float sn, cs;
    sincosf(ang, &sn, &cs);

    const size_t off = (size_t)row * D_MODEL + pair * 2;
    float2 vq = *(float2*)(q + off);
    float2 vk = *(float2*)(k + off);
    float2 rq, rk;
    rq.x = vq.x * cs - vq.y * sn;  rq.y = vq.x * sn + vq.y * cs;
    rk.x = vk.x * cs - vk.y * sn;  rk.y = vk.x * sn + vk.y * cs;
    *(float2*)(q + off) = rq;
    *(float2*)(k + off) = rk;
}

// ---------------------------------------------------------------------------
// MFMA flash attention, bf16x3 split precision, causal. Layout (b,s,h*128+d).
// Block = 256 thr = 4 waves; wave w owns q-rows [qb+32w, qb+32w+32); block
// covers 128 q-rows; all waves share K/V LDS tiles of 64 kv-rows.
// Swapped QK^T: S^T = K·Q^T via mfma(K-frag, Q-frag) -> per-lane softmax
// columns (2 per lane). P^T -> PV A-frags via in-register shfl gather
// (fs=2ks+(g>>1), g_s=2(g&1)+(e>>2), j=e&3 — re-verified twice).
// V staged TRANSPOSED ([d][kv]) with 2-bit XOR slot swizzle on write+read;
// both hot LDS reads proved balanced at 8 lanes per 4-bank group.
// ---------------------------------------------------------------------------
#define ABM 128
#define AWQ 32
#define KVT 64
#define KLD 136   // K LDS row stride (shorts): 128 data + 8 pad (17 slots)
#define VLD 72    // V^T LDS row stride (shorts): 64 data + 8 pad

__global__ __launch_bounds__(256, 2) void flash_attn_mfma(const float* __restrict__ Q,
                                                          const float* __restrict__ K,
                                                          const float* __restrict__ V,
                                                          float* __restrict__ O)
{
    __shared__ __align__(16) short KhS[KVT * KLD];
    __shared__ __align__(16) short KlS[KVT * KLD];
    __shared__ __align__(16) short VTh[DK * VLD];
    __shared__ __align__(16) short VTl[DK * VLD];

    const int tid  = threadIdx.x;
    const int lane = tid & 63;
    const int w    = tid >> 6;
    const int l16  = lane & 15;
    const int g    = lane >> 4;           // 0..3
    const int h    = blockIdx.y & (NHEAD - 1);
    const int b    = blockIdx.y >> 4;
    const size_t base = (size_t)b * SEQ * D_MODEL + (size_t)h * DK;
    const int qb  = blockIdx.x * ABM;
    const int qw0 = qb + w * AWQ;         // wave's first q-row
    const float scale = 0.08838834764831845f;  // 1/sqrt(128)

    // ---- Q B-operand fragments, registers, loaded once from global.
    short8 qh[2][4], ql[2][4];
#pragma unroll
    for (int fq = 0; fq < 2; ++fq)
#pragma unroll
        for (int ks = 0; ks < 4; ++ks) {
            const float* src = Q + base + (size_t)(qw0 + fq * 16 + l16) * D_MODEL + g * 8 + ks * 32;
            float4 f0 = *(const float4*)src;
            float4 f1 = *(const float4*)(src + 4);
            float f[8] = {f0.x, f0.y, f0.z, f0.w, f1.x, f1.y, f1.z, f1.w};
            short8 hh, ll;
#pragma unroll
            for (int e = 0; e < 8; ++e) {
                short hb = f2bf(f[e]); hh[e] = hb; ll[e] = f2bf(f[e] - bf2f(hb));
            }
            qh[fq][ks] = hh; ql[fq][ks] = ll;
        }

    f32x4 accO[2][8];
#pragma unroll
    for (int i = 0; i < 2; ++i)
#pragma unroll
        for (int j = 0; j < 8; ++j) accO[i][j] = (f32x4)0.0f;
    float mstate[2] = {-3.0e38f, -3.0e38f};
    float lstate[2] = {0.f, 0.f};

    const int nt = (qb + ABM) / KVT;      // kv tiles
    for (int t = 0; t < nt; ++t) {
        const int kv0 = t * KVT;
        __syncthreads();                  // prior tile's readers done

        // ---- stage K tile [64 kv][128 d] hi/lo, row-major, stride KLD
        {
            const int r  = tid >> 2;
            const int d0 = (tid & 3) * 32;
            const float* src = K + base + (size_t)(kv0 + r) * D_MODEL + d0;
#pragma unroll
            for (int u = 0; u < 4; ++u) {
                float4 f0 = *(const float4*)(src + u * 8);
                float4 f1 = *(const float4*)(src + u * 8 + 4);
                float f[8] = {f0.x, f0.y, f0.z, f0.w, f1.x, f1.y, f1.z, f1.w};
                short8 hh, ll;
#pragma unroll
                for (int e = 0; e < 8; ++e) {
                    short hb = f2bf(f[e]); hh[e] = hb; ll[e] = f2bf(f[e] - bf2f(hb));
                }
                *(short8*)&KhS[r * KLD + d0 + u * 8] = hh;
                *(short8*)&KlS[r * KLD + d0 + u * 8] = ll;
            }
        }
        // ---- stage V TRANSPOSED: VT[d][kv], XOR slot swizzle both sides
#pragma unroll
        for (int it = 0; it < 2; ++it) {
            const int tt  = tid + it * 256;
            const int dq  = tt & 31;      // d quad
            const int kvq = tt >> 5;      // kv quad 0..15
            const float* vs = V + base + (size_t)(kv0 + kvq * 4) * D_MODEL + dq * 4;
            float4 r0 = *(const float4*)(vs);
            float4 r1 = *(const float4*)(vs + D_MODEL);
            float4 r2 = *(const float4*)(vs + 2 * D_MODEL);
            float4 r3 = *(const float4*)(vs + 3 * D_MODEL);
            float vals[4][4] = {{r0.x,r0.y,r0.z,r0.w},{r1.x,r1.y,r1.z,r1.w},
                                {r2.x,r2.y,r2.z,r2.w},{r3.x,r3.y,r3.z,r3.w}};
#pragma unroll
            for (int c = 0; c < 4; ++c) {
                const int r   = dq * 4 + c;                    // d-row of V^T
                const int sw  = ((r >> 2) ^ (r >> 4)) & 3;
                const int off = r * VLD + (((kvq >> 1) ^ sw) << 3) + ((kvq & 1) << 2);
                shortx4 hh, ll;
#pragma unroll
                for (int i = 0; i < 4; ++i) {
                    float f = vals[i][c];
                    short hb = f2bf(f); hh[i] = hb; ll[i] = f2bf(f - bf2f(hb));
                }
                *(shortx4*)&VTh[off] = hh;
                *(shortx4*)&VTl[off] = ll;
            }
        }
        __syncthreads();

        const bool active = (kv0 <= qw0 + AWQ - 1);   // wave-uniform
        if (active) {
            // ---- QK^T (swapped): S^T[kv][q] = K·Q^T, x3 split
            f32x4 accS[4][2];
#pragma unroll
            for (int i = 0; i < 4; ++i) { accS[i][0] = (f32x4)0.0f; accS[i][1] = (f32x4)0.0f; }
#pragma unroll
            for (int ks = 0; ks < 4; ++ks) {
#pragma unroll
                for (int fs = 0; fs < 4; ++fs) {
                    const short8 kh = *(const short8*)&KhS[(fs * 16 + l16) * KLD + g * 8 + ks * 32];
                    const short8 kl = *(const short8*)&KlS[(fs * 16 + l16) * KLD + g * 8 + ks * 32];
#pragma unroll
                    for (int fq = 0; fq < 2; ++fq) {
                        accS[fs][fq] = __builtin_amdgcn_mfma_f32_16x16x32_bf16(kh, qh[fq][ks], accS[fs][fq], 0, 0, 0);
                        accS[fs][fq] = __builtin_amdgcn_mfma_f32_16x16x32_bf16(kh, ql[fq][ks], accS[fs][fq], 0, 0, 0);
                        accS[fs][fq] = __builtin_amdgcn_mfma_f32_16x16x32_bf16(kl, qh[fq][ks], accS[fs][fq], 0, 0, 0);
                    }
                }
            }

            // ---- online softmax on columns q = qw0 + fq*16 + l16
            const bool needmask = (kv0 + KVT - 1 > qw0);
            float al[2];
#pragma unroll
            for (int fq = 0; fq < 2; ++fq) {
                const int qg = qw0 + fq * 16 + l16;
                float mx = -3.0e38f;
#pragma unroll
                for (int fs = 0; fs < 4; ++fs)
#pragma unroll
                    for (int j = 0; j < 4; ++j) {
                        float s = accS[fs][fq][j] * scale;
                        if (needmask) {
                            const int kvg = kv0 + fs * 16 + g * 4 + j;
                            s = (kvg <= qg) ? s : -3.0e38f;
                        }
                        accS[fs][fq][j] = s;
                        mx = fmaxf(mx, s);
                    }
                mx = fmaxf(mx, __shfl_xor(mx, 16));
                mx = fmaxf(mx, __shfl_xor(mx, 32));
                const float mnew = fmaxf(mstate[fq], mx);
                al[fq] = __expf(mstate[fq] - mnew);
                mstate[fq] = mnew;
                float sm = 0.f;
#pragma unroll
                for (int fs = 0; fs < 4; ++fs)
#pragma unroll
                    for (int j = 0; j < 4; ++j) {
                        const float p = __expf(accS[fs][fq][j] - mnew);  // masked -> 0
                        accS[fs][fq][j] = p;
                        sm += p;
                    }
                sm += __shfl_xor(sm, 16);
                sm += __shfl_xor(sm, 32);
                lstate[fq] = lstate[fq] * al[fq] + sm;
            }

            // ---- rescale O rows (row q = fm*16 + 4g + j; state at lane l16=4g+j)
            float alr[2][4];
#pragma unroll
            for (int fm = 0; fm < 2; ++fm)
#pragma unroll
                for (int j = 0; j < 4; ++j)
                    alr[fm][j] = __shfl(al[fm], (g << 2) | j);
#pragma unroll
            for (int fm = 0; fm < 2; ++fm)
#pragma unroll
                for (int fd = 0; fd < 8; ++fd)
#pragma unroll
                    for (int j = 0; j < 4; ++j)
                        accO[fm][fd][j] *= alr[fm][j];

            // ---- PV: O += P·V, x3. P^T gathered from accS via shfl.
#pragma unroll
            for (int ks = 0; ks < 2; ++ks) {
                short8 pah[2], pal[2];
#pragma unroll
                for (int fm = 0; fm < 2; ++fm) {
                    float pv[8];
#pragma unroll
                    for (int e = 0; e < 8; ++e) {
                        const int j = e & 3;
                        const int srcl = ((((lane >> 4) & 1) << 1) + (e >> 2)) * 16 + l16;
                        const float c0 = __shfl(accS[2 * ks][fm][j], srcl);
                        const float c1 = __shfl(accS[2 * ks + 1][fm][j], srcl);
                        pv[e] = (g >> 1) ? c1 : c0;
                    }
                    short8 hh, ll;
#pragma unroll
                    for (int e = 0; e < 8; ++e) {
                        short hb = f2bf(pv[e]); hh[e] = hb; ll[e] = f2bf(pv[e] - bf2f(hb));
                    }
                    pah[fm] = hh; pal[fm] = ll;
                }
#pragma unroll
                for (int fd = 0; fd < 8; ++fd) {
                    const int r = fd * 16 + l16;
                    const int sw = ((r >> 2) ^ (r >> 4)) & 3;
                    const int off = r * VLD + (((g + 4 * ks) ^ sw) << 3);
                    const short8 vh = *(const short8*)&VTh[off];
                    const short8 vl = *(const short8*)&VTl[off];
#pragma unroll
                    for (int fm = 0; fm < 2; ++fm) {
                        accO[fm][fd] = __builtin_amdgcn_mfma_f32_16x16x32_bf16(pah[fm], vh, accO[fm][fd], 0, 0, 0);
                        accO[fm][fd] = __builtin_amdgcn_mfma_f32_16x16x32_bf16(pah[fm], vl, accO[fm][fd], 0, 0, 0);
                        accO[fm][fd] = __builtin_amdgcn_mfma_f32_16x16x32_bf16(pal[fm], vh, accO[fm][fd], 0, 0, 0);
                    }
                }
            }
        } // active
    } // tiles

    // ---- epilogue: O /= l, write out
    float rl[2][4];
#pragma unroll
    for (int fm = 0; fm < 2; ++fm)
#pragma unroll
        for (int j = 0; j < 4; ++j)
            rl[fm][j] = 1.0f / __shfl(lstate[fm], (g << 2) | j);
#pragma unroll
    for (int fm = 0; fm < 2; ++fm)
#pragma unroll
        for (int j = 0; j < 4; ++j) {
            const size_t row = base + (size_t)(qw0 + fm * 16 + 4 * g + j) * D_MODEL;
#pragma unroll
            for (int fd = 0; fd < 8; ++fd)
                O[row + fd * 16 + l16] = accO[fm][fd][j] * rl[fm][j];
        }
}

// ---------------------------------------------------------------------------
extern "C" void kernel_launch(void* const* d_in, const int* in_sizes, int n_in,
                              void* d_out, int out_size, void* d_ws, size_t ws_size,
                              hipStream_t stream)
{
    const float* x  = (const float*)d_in[0];
    const int*  pos = (const int*)d_in[1];
    const float* wq = (const float*)d_in[2];
    const float* wk = (const float*)d_in[3];
    const float* wv = (const float*)d_in[4];
    const float* wo = (const float*)d_in[5];
    float* out = (float*)d_out;

    const size_t bufElems = (size_t)MROWS * D_MODEL;  // 32 MiB each
    float* q  = (float*)d_ws;
    float* k  = q + bufElems;
    float* v  = k + bufElems;
    float* ao = v + bufElems;                          // total ws use: 128 MiB

    const dim3 blk(256);
    const dim3 ggrid(D_MODEL / GBN, MROWS / GBM);      // (16, 32)

    gemm_nt_mfma<<<ggrid, blk, 0, stream>>>(x, wq, q, MROWS, D_MODEL, D_MODEL);
    gemm_nt_mfma<<<ggrid, blk, 0, stream>>>(x, wk, k, MROWS, D_MODEL, D_MODEL);
    gemm_nt_mfma<<<ggrid, blk, 0, stream>>>(x, wv, v, MROWS, D_MODEL, D_MODEL);

    rope_kernel<<<(MROWS * 1024 + 255) / 256, blk, 0, stream>>>(q, k, pos);

    flash_attn_mfma<<<dim3(SEQ / ABM, BATCH * NHEAD), blk, 0, stream>>>(q, k, v, ao);

    gemm_nt_mfma<<<ggrid, blk, 0, stream>>>(ao, wo, out, MROWS, D_MODEL, D_MODEL);
}

// Round 7
// 836.655 us; speedup vs baseline: 1.0164x; 1.0164x over previous
//
#include <hip/hip_runtime.h>
#include <hip/hip_bf16.h>
#include <math.h>

// Problem constants (fixed by the reference)
#define D_MODEL 2048
#define NHEAD   16
#define DK      128
#define SEQ     2048
#define BATCH   2
#define MROWS   (BATCH*SEQ)   // 4096 rows of (b,s)

typedef __attribute__((ext_vector_type(8))) short short8;
typedef __attribute__((ext_vector_type(4))) short shortx4;
typedef __attribute__((ext_vector_type(4))) float f32x4;

static __device__ __forceinline__ short f2bf(float v) {
    union { __hip_bfloat16 b; short s; } u;
    u.b = __float2bfloat16(v);
    return u.s;
}
static __device__ __forceinline__ float bf2f(short s) {
    union { short s; __hip_bfloat16 b; } u;
    u.s = s;
    return __bfloat162float(u.b);
}

// ---------------------------------------------------------------------------
// Elementwise fp32 -> (hi,lo) bf16 split. Bit-identical to the in-GEMM split.
// ---------------------------------------------------------------------------
__global__ __launch_bounds__(256) void split_bf16(const float* __restrict__ in,
                                                  short* __restrict__ hi,
                                                  short* __restrict__ lo, int n8)
{
    int i = blockIdx.x * 256 + threadIdx.x;
    const int stride = gridDim.x * 256;
    for (; i < n8; i += stride) {
        const float4 a = ((const float4*)in)[2 * i];
        const float4 b = ((const float4*)in)[2 * i + 1];
        const float f[8] = {a.x, a.y, a.z, a.w, b.x, b.y, b.z, b.w};
        short8 h, l;
#pragma unroll
        for (int e = 0; e < 8; ++e) {
            const short hb = f2bf(f[e]); h[e] = hb; l[e] = f2bf(f[e] - bf2f(hb));
        }
        ((short8*)hi)[i] = h;
        ((short8*)lo)[i] = l;
    }
}

// ---------------------------------------------------------------------------
// bf16x3 MFMA GEMM, PRE-SPLIT inputs: C = A*W^T, A/W given as bf16 hi/lo.
// Same tile/fragment structure as the verified legacy kernel; staging is a
// pure short8 copy (no VALU convert in the loop).
// ---------------------------------------------------------------------------
#define GBM 128
#define GBN 128
#define GBK 32
#define LDKG 40   // shorts per LDS row: 32 data + 8 pad (80 B)

__global__ __launch_bounds__(256, 2) void gemm_nt_bf(const short* __restrict__ Ahg,
                                                     const short* __restrict__ Alg,
                                                     const short* __restrict__ Whg,
                                                     const short* __restrict__ Wlg,
                                                     float* __restrict__ C,
                                                     int M, int N, int K)
{
    __shared__ __align__(16) short Ah[GBM][LDKG];
    __shared__ __align__(16) short Al[GBM][LDKG];
    __shared__ __align__(16) short Bh[GBN][LDKG];
    __shared__ __align__(16) short Bl[GBN][LDKG];

    const int tid  = threadIdx.x;
    const int lane = tid & 63;
    const int w    = tid >> 6;
    const int wm   = (w & 1) * 64;
    const int wn   = (w >> 1) * 64;
    const int l16  = lane & 15;
    const int kb   = (lane >> 4) * 8;

    const size_t row0 = (size_t)blockIdx.y * GBM;
    const size_t col0 = (size_t)blockIdx.x * GBN;

    const int sr0 = tid >> 2;
    const int sr1 = sr0 + 64;
    const int skc = (tid & 3) * 8;

    f32x4 acc[4][4];
#pragma unroll
    for (int i = 0; i < 4; ++i)
#pragma unroll
        for (int j = 0; j < 4; ++j) acc[i][j] = (f32x4)0.0f;

    short8 ra0h = *(const short8*)(Ahg + (row0 + sr0) * K + skc);
    short8 ra0l = *(const short8*)(Alg + (row0 + sr0) * K + skc);
    short8 ra1h = *(const short8*)(Ahg + (row0 + sr1) * K + skc);
    short8 ra1l = *(const short8*)(Alg + (row0 + sr1) * K + skc);
    short8 rw0h = *(const short8*)(Whg + (col0 + sr0) * K + skc);
    short8 rw0l = *(const short8*)(Wlg + (col0 + sr0) * K + skc);
    short8 rw1h = *(const short8*)(Whg + (col0 + sr1) * K + skc);
    short8 rw1l = *(const short8*)(Wlg + (col0 + sr1) * K + skc);

    for (int kt = 0; kt < K; kt += GBK) {
        *(short8*)&Ah[sr0][skc] = ra0h;  *(short8*)&Al[sr0][skc] = ra0l;
        *(short8*)&Ah[sr1][skc] = ra1h;  *(short8*)&Al[sr1][skc] = ra1l;
        *(short8*)&Bh[sr0][skc] = rw0h;  *(short8*)&Bl[sr0][skc] = rw0l;
        *(short8*)&Bh[sr1][skc] = rw1h;  *(short8*)&Bl[sr1][skc] = rw1l;
        __syncthreads();

        if (kt + GBK < K) {
            const int kn = kt + GBK;
            ra0h = *(const short8*)(Ahg + (row0 + sr0) * K + kn + skc);
            ra0l = *(const short8*)(Alg + (row0 + sr0) * K + kn + skc);
            ra1h = *(const short8*)(Ahg + (row0 + sr1) * K + kn + skc);
            ra1l = *(const short8*)(Alg + (row0 + sr1) * K + kn + skc);
            rw0h = *(const short8*)(Whg + (col0 + sr0) * K + kn + skc);
            rw0l = *(const short8*)(Wlg + (col0 + sr0) * K + kn + skc);
            rw1h = *(const short8*)(Whg + (col0 + sr1) * K + kn + skc);
            rw1l = *(const short8*)(Wlg + (col0 + sr1) * K + kn + skc);
        }

        short8 bh[4], bl[4];
#pragma unroll
        for (int fn = 0; fn < 4; ++fn) {
            bh[fn] = *(const short8*)&Bh[wn + fn * 16 + l16][kb];
            bl[fn] = *(const short8*)&Bl[wn + fn * 16 + l16][kb];
        }
#pragma unroll
        for (int fm = 0; fm < 4; ++fm) {
            const short8 ah = *(const short8*)&Ah[wm + fm * 16 + l16][kb];
            const short8 al = *(const short8*)&Al[wm + fm * 16 + l16][kb];
#pragma unroll
            for (int fn = 0; fn < 4; ++fn) {
                acc[fm][fn] = __builtin_amdgcn_mfma_f32_16x16x32_bf16(ah, bh[fn], acc[fm][fn], 0, 0, 0);
                acc[fm][fn] = __builtin_amdgcn_mfma_f32_16x16x32_bf16(ah, bl[fn], acc[fm][fn], 0, 0, 0);
                acc[fm][fn] = __builtin_amdgcn_mfma_f32_16x16x32_bf16(al, bh[fn], acc[fm][fn], 0, 0, 0);
            }
        }
        __syncthreads();
    }

#pragma unroll
    for (int fm = 0; fm < 4; ++fm) {
#pragma unroll
        for (int j = 0; j < 4; ++j) {
            const size_t r = row0 + wm + fm * 16 + (lane >> 4) * 4 + j;
#pragma unroll
            for (int fn = 0; fn < 4; ++fn)
                C[r * N + col0 + wn + fn * 16 + l16] = acc[fm][fn][j];
        }
    }
}

// ---------------------------------------------------------------------------
// LEGACY bf16x3 GEMM (fp32 in, in-loop split) — fallback if ws too small.
// ---------------------------------------------------------------------------
__global__ __launch_bounds__(256, 2) void gemm_nt_mfma(const float* __restrict__ A,
                                                       const float* __restrict__ W,
                                                       float* __restrict__ C,
                                                       int M, int N, int K)
{
    __shared__ __align__(16) short Ah[GBM][LDKG];
    __shared__ __align__(16) short Al[GBM][LDKG];
    __shared__ __align__(16) short Bh[GBN][LDKG];
    __shared__ __align__(16) short Bl[GBN][LDKG];

    const int tid  = threadIdx.x;
    const int lane = tid & 63;
    const int w    = tid >> 6;
    const int wm   = (w & 1) * 64;
    const int wn   = (w >> 1) * 64;
    const int l16  = lane & 15;
    const int kb   = (lane >> 4) * 8;

    const size_t row0 = (size_t)blockIdx.y * GBM;
    const size_t col0 = (size_t)blockIdx.x * GBN;

    const int sr0 = tid >> 2;
    const int sr1 = sr0 + 64;
    const int skc = (tid & 3) * 8;

    f32x4 acc[4][4];
#pragma unroll
    for (int i = 0; i < 4; ++i)
#pragma unroll
        for (int j = 0; j < 4; ++j) acc[i][j] = (f32x4)0.0f;

    float4 pa0a = *(const float4*)(A + (row0 + sr0) * K + skc);
    float4 pa0b = *(const float4*)(A + (row0 + sr0) * K + skc + 4);
    float4 pa1a = *(const float4*)(A + (row0 + sr1) * K + skc);
    float4 pa1b = *(const float4*)(A + (row0 + sr1) * K + skc + 4);
    float4 pw0a = *(const float4*)(W + (col0 + sr0) * K + skc);
    float4 pw0b = *(const float4*)(W + (col0 + sr0) * K + skc + 4);
    float4 pw1a = *(const float4*)(W + (col0 + sr1) * K + skc);
    float4 pw1b = *(const float4*)(W + (col0 + sr1) * K + skc + 4);

    for (int kt = 0; kt < K; kt += GBK) {
        {
            float f[8]; short8 h, l;
#define CVT8(va, vb)                                                        \
            f[0]=va.x; f[1]=va.y; f[2]=va.z; f[3]=va.w;                     \
            f[4]=vb.x; f[5]=vb.y; f[6]=vb.z; f[7]=vb.w;                     \
            _Pragma("unroll")                                               \
            for (int j = 0; j < 8; ++j) {                                   \
                short hb = f2bf(f[j]); h[j] = hb; l[j] = f2bf(f[j] - bf2f(hb)); \
            }
            CVT8(pa0a, pa0b)
            *(short8*)&Ah[sr0][skc] = h;  *(short8*)&Al[sr0][skc] = l;
            CVT8(pa1a, pa1b)
            *(short8*)&Ah[sr1][skc] = h;  *(short8*)&Al[sr1][skc] = l;
            CVT8(pw0a, pw0b)
            *(short8*)&Bh[sr0][skc] = h;  *(short8*)&Bl[sr0][skc] = l;
            CVT8(pw1a, pw1b)
            *(short8*)&Bh[sr1][skc] = h;  *(short8*)&Bl[sr1][skc] = l;
#undef CVT8
        }
        __syncthreads();

        if (kt + GBK < K) {
            const int kn = kt + GBK;
            pa0a = *(const float4*)(A + (row0 + sr0) * K + kn + skc);
            pa0b = *(const float4*)(A + (row0 + sr0) * K + kn + skc + 4);
            pa1a = *(const float4*)(A + (row0 + sr1) * K + kn + skc);
            pa1b = *(const float4*)(A + (row0 + sr1) * K + kn + skc + 4);
            pw0a = *(const float4*)(W + (col0 + sr0) * K + kn + skc);
            pw0b = *(const float4*)(W + (col0 + sr0) * K + kn + skc + 4);
            pw1a = *(const float4*)(W + (col0 + sr1) * K + kn + skc);
            pw1b = *(const float4*)(W + (col0 + sr1) * K + kn + skc + 4);
        }

        short8 bh[4], bl[4];
#pragma unroll
        for (int fn = 0; fn < 4; ++fn) {
            bh[fn] = *(const short8*)&Bh[wn + fn * 16 + l16][kb];
            bl[fn] = *(const short8*)&Bl[wn + fn * 16 + l16][kb];
        }
#pragma unroll
        for (int fm = 0; fm < 4; ++fm) {
            const short8 ah = *(const short8*)&Ah[wm + fm * 16 + l16][kb];
            const short8 al = *(const short8*)&Al[wm + fm * 16 + l16][kb];
#pragma unroll
            for (int fn = 0; fn < 4; ++fn) {
                acc[fm][fn] = __builtin_amdgcn_mfma_f32_16x16x32_bf16(ah, bh[fn], acc[fm][fn], 0, 0, 0);
                acc[fm][fn] = __builtin_amdgcn_mfma_f32_16x16x32_bf16(ah, bl[fn], acc[fm][fn], 0, 0, 0);
                acc[fm][fn] = __builtin_amdgcn_mfma_f32_16x16x32_bf16(al, bh[fn], acc[fm][fn], 0, 0, 0);
            }
        }
        __syncthreads();
    }

#pragma unroll
    for (int fm = 0; fm < 4; ++fm) {
#pragma unroll
        for (int j = 0; j < 4; ++j) {
            const size_t r = row0 + wm + fm * 16 + (lane >> 4) * 4 + j;
#pragma unroll
            for (int fn = 0; fn < 4; ++fn)
                C[r * N + col0 + wn + fn * 16 + l16] = acc[fm][fn][j];
        }
    }
}

// ---------------------------------------------------------------------------
// RoPE (in-place on q and k), double-precision inv_freq.
// ---------------------------------------------------------------------------
__global__ __launch_bounds__(256) void rope_kernel(float* __restrict__ q,
                                                   float* __restrict__ k,
                                                   const int* __restrict__ pos)
{
    const int idx = blockIdx.x * 256 + threadIdx.x;
    if (idx >= MROWS * 1024) return;
    const int pair = idx & 1023;
    const int row  = idx >> 10;
    const int s    = row & (SEQ - 1);
    const int j    = pair & 63;

    const float inv_freq = (float)pow(10000.0, -(double)(2 * j) / 128.0);
    const float ang = (float)pos[s] * inv_freq;
    float sn, cs;
    sincosf(ang, &sn, &cs);

    const size_t off = (size_t)row * D_MODEL + pair * 2;
    float2 vq = *(float2*)(q + off);
    float2 vk = *(float2*)(k + off);
    float2 rq, rk;
    rq.x = vq.x * cs - vq.y * sn;  rq.y = vq.x * sn + vq.y * cs;
    rk.x = vk.x * cs - vk.y * sn;  rk.y = vk.x * sn + vk.y * cs;
    *(float2*)(q + off) = rq;
    *(float2*)(k + off) = rk;
}

// ---------------------------------------------------------------------------
// MFMA flash attention, bf16x3, causal. PAIRED q-tiles (qt, 15-qt) per block
// for perfect causal load balance (34 kv-steps per block, 256 blocks = 1/CU).
// Double-buffered LDS (136 KB) + async-stage split: next tile's global loads
// issue before compute (latency hidden under MFMA); convert+LDS-write lands
// after compute into the other buffer. ONE barrier per step:
//   writes to buf[cur^1] at step st happen after barrier(st), which is after
//   all waves finished reading buf[cur^1] at step st-1; reads of buf[cur^1]
//   at st+1 are gated by barrier(st+1). No other LDS hazards.
// K tile stored with 16B-slot XOR swizzle (slot ^= row&7, 256 B rows):
// both staging writes and fragment reads provably balanced (8 lanes/class).
// ---------------------------------------------------------------------------
#define ABM 128
#define AWQ 32
#define KVT 64
#define KROW 128  // K LDS row stride in shorts (256 B = 16 slots of 16 B)
#define VLD 72    // V^T LDS row stride in shorts (64 data + 8 pad)

__device__ __forceinline__ void attn_issue_loads(const float* __restrict__ K,
                                                 const float* __restrict__ V,
                                                 size_t base, int kv0, int tid,
                                                 float4* kreg, float4* vreg)
{
    const int r  = tid >> 2;
    const int d0 = (tid & 3) * 32;
    const float* ksrc = K + base + (size_t)(kv0 + r) * D_MODEL + d0;
#pragma unroll
    for (int u = 0; u < 4; ++u) {
        kreg[2 * u]     = *(const float4*)(ksrc + u * 8);
        kreg[2 * u + 1] = *(const float4*)(ksrc + u * 8 + 4);
    }
#pragma unroll
    for (int it = 0; it < 2; ++it) {
        const int tt  = tid + it * 256;
        const int dq  = tt & 31;
        const int kvq = tt >> 5;
        const float* vs = V + base + (size_t)(kv0 + kvq * 4) * D_MODEL + dq * 4;
#pragma unroll
        for (int i = 0; i < 4; ++i)
            vreg[it * 4 + i] = *(const float4*)(vs + i * D_MODEL);
    }
}

__device__ __forceinline__ void attn_convert_write(short* __restrict__ KhS,
                                                   short* __restrict__ KlS,
                                                   short* __restrict__ VTh,
                                                   short* __restrict__ VTl,
                                                   int tid,
                                                   const float4* kreg,
                                                   const float4* vreg)
{
    const int r = tid >> 2;
#pragma unroll
    for (int u = 0; u < 4; ++u) {
        const float4 f0 = kreg[2 * u];
        const float4 f1 = kreg[2 * u + 1];
        const float f[8] = {f0.x, f0.y, f0.z, f0.w, f1.x, f1.y, f1.z, f1.w};
        short8 hh, ll;
#pragma unroll
        for (int e = 0; e < 8; ++e) {
            const short hb = f2bf(f[e]); hh[e] = hb; ll[e] = f2bf(f[e] - bf2f(hb));
        }
        const int off = r * KROW + (((4 * (tid & 3) + u) ^ (r & 7)) << 3);
        *(short8*)&KhS[off] = hh;
        *(short8*)&KlS[off] = ll;
    }
#pragma unroll
    for (int it = 0; it < 2; ++it) {
        const int tt  = tid + it * 256;
        const int dq  = tt & 31;
        const int kvq = tt >> 5;
        const float4 r0 = vreg[it * 4 + 0];
        const float4 r1 = vreg[it * 4 + 1];
        const float4 r2 = vreg[it * 4 + 2];
        const float4 r3 = vreg[it * 4 + 3];
        const float vals[4][4] = {{r0.x, r0.y, r0.z, r0.w}, {r1.x, r1.y, r1.z, r1.w},
                                  {r2.x, r2.y, r2.z, r2.w}, {r3.x, r3.y, r3.z, r3.w}};
#pragma unroll
        for (int c = 0; c < 4; ++c) {
            const int rr  = dq * 4 + c;
            const int sw  = ((rr >> 2) ^ (rr >> 4)) & 3;
            const int off = rr * VLD + (((kvq >> 1) ^ sw) << 3) + ((kvq & 1) << 2);
            shortx4 hh, ll;
#pragma unroll
            for (int i = 0; i < 4; ++i) {
                const float fv = vals[i][c];
                const short hb = f2bf(fv); hh[i] = hb; ll[i] = f2bf(fv - bf2f(hb));
            }
            *(shortx4*)&VTh[off] = hh;
            *(shortx4*)&VTl[off] = ll;
        }
    }
}

__device__ __forceinline__ void attn_load_q(const float* __restrict__ Q, size_t base,
                                            int qw0, int l16, int g,
                                            short8 qh[2][4], short8 ql[2][4])
{
#pragma unroll
    for (int fq = 0; fq < 2; ++fq)
#pragma unroll
        for (int ks = 0; ks < 4; ++ks) {
            const float* src = Q + base + (size_t)(qw0 + fq * 16 + l16) * D_MODEL + g * 8 + ks * 32;
            const float4 f0 = *(const float4*)src;
            const float4 f1 = *(const float4*)(src + 4);
            const float f[8] = {f0.x, f0.y, f0.z, f0.w, f1.x, f1.y, f1.z, f1.w};
            short8 hh, ll;
#pragma unroll
            for (int e = 0; e < 8; ++e) {
                const short hb = f2bf(f[e]); hh[e] = hb; ll[e] = f2bf(f[e] - bf2f(hb));
            }
            qh[fq][ks] = hh; ql[fq][ks] = ll;
        }
}

__device__ __forceinline__ void attn_write_o(float* __restrict__ O, size_t base,
                                             int qw0, int g, int l16,
                                             const f32x4 accO[2][8], const float lstate[2])
{
    float rl[2][4];
#pragma unroll
    for (int fm = 0; fm < 2; ++fm)
#pragma unroll
        for (int j = 0; j < 4; ++j)
            rl[fm][j] = 1.0f / __shfl(lstate[fm], (g << 2) | j);
#pragma unroll
    for (int fm = 0; fm < 2; ++fm)
#pragma unroll
        for (int j = 0; j < 4; ++j) {
            const size_t row = base + (size_t)(qw0 + fm * 16 + 4 * g + j) * D_MODEL;
#pragma unroll
            for (int fd = 0; fd < 8; ++fd)
                O[row + fd * 16 + l16] = accO[fm][fd][j] * rl[fm][j];
        }
}

__global__ __launch_bounds__(256, 1) void flash_attn_mfma(const float* __restrict__ Q,
                                                          const float* __restrict__ K,
                                                          const float* __restrict__ V,
                                                          float* __restrict__ O)
{
    __shared__ __align__(16) short KhS[2][KVT * KROW];
    __shared__ __align__(16) short KlS[2][KVT * KROW];
    __shared__ __align__(16) short VTh[2][DK * VLD];
    __shared__ __align__(16) short VTl[2][DK * VLD];

    const int tid  = threadIdx.x;
    const int lane = tid & 63;
    const int w    = tid >> 6;
    const int l16  = lane & 15;
    const int g    = lane >> 4;
    const int h    = blockIdx.y & (NHEAD - 1);
    const int b    = blockIdx.y >> 4;
    const size_t base = (size_t)b * SEQ * D_MODEL + (size_t)h * DK;
    const float scale = 0.08838834764831845f;  // 1/sqrt(128)

    const int qtA = blockIdx.x;        // 0..7
    const int qtB = 15 - qtA;          // 8..15; work = (2qtA+2)+(2qtB+2) = 34
    const int ntA = 2 * qtA + 2;
    const int total = 34;

    short8 qh[2][4], ql[2][4];
    attn_load_q(Q, base, qtA * ABM + w * AWQ, l16, g, qh, ql);

    f32x4 accO[2][8];
#pragma unroll
    for (int i = 0; i < 2; ++i)
#pragma unroll
        for (int j = 0; j < 8; ++j) accO[i][j] = (f32x4)0.0f;
    float mstate[2] = {-3.0e38f, -3.0e38f};
    float lstate[2] = {0.f, 0.f};

    float4 kreg[8], vreg[8];
    // prologue: stage stream tile 0 (pass A, kv0 = 0) into buffer 0
    attn_issue_loads(K, V, base, 0, tid, kreg, vreg);
    attn_convert_write(KhS[0], KlS[0], VTh[0], VTl[0], tid, kreg, vreg);
    int cur = 0;

    for (int st = 0; st < total; ++st) {
        const int pass = (st >= ntA) ? 1 : 0;
        const int t    = pass ? (st - ntA) : st;
        const int qt   = pass ? qtB : qtA;
        const int kv0  = t * KVT;
        const int qw0  = qt * ABM + w * AWQ;

        __syncthreads();   // buf[cur] staged; all waves done reading buf[cur^1]

        // issue next stream tile's global loads (latency hides under compute)
        if (st + 1 < total) {
            const int t2 = (st + 1 >= ntA) ? (st + 1 - ntA) : (st + 1);
            attn_issue_loads(K, V, base, t2 * KVT, tid, kreg, vreg);
        }

        if (pass && t == 0) {
            // pass-A epilogue + switch to pass-B q-tile
            attn_write_o(O, base, qtA * ABM + w * AWQ, g, l16, accO, lstate);
            attn_load_q(Q, base, qtB * ABM + w * AWQ, l16, g, qh, ql);
#pragma unroll
            for (int i = 0; i < 2; ++i)
#pragma unroll
                for (int j = 0; j < 8; ++j) accO[i][j] = (f32x4)0.0f;
            mstate[0] = mstate[1] = -3.0e38f;
            lstate[0] = lstate[1] = 0.f;
        }

        const bool active = (kv0 <= qw0 + AWQ - 1);   // wave-uniform
        if (active) {
            // ---- QK^T (swapped): S^T = K·Q^T, x3 split
            f32x4 accS[4][2];
#pragma unroll
            for (int i = 0; i < 4; ++i) { accS[i][0] = (f32x4)0.0f; accS[i][1] = (f32x4)0.0f; }
#pragma unroll
            for (int ks = 0; ks < 4; ++ks) {
#pragma unroll
                for (int fs = 0; fs < 4; ++fs) {
                    const int koff = (fs * 16 + l16) * KROW + (((g + 4 * ks) ^ (l16 & 7)) << 3);
                    const short8 kh = *(const short8*)&KhS[cur][koff];
                    const short8 kl = *(const short8*)&KlS[cur][koff];
#pragma unroll
                    for (int fq = 0; fq < 2; ++fq) {
                        accS[fs][fq] = __builtin_amdgcn_mfma_f32_16x16x32_bf16(kh, qh[fq][ks], accS[fs][fq], 0, 0, 0);
                        accS[fs][fq] = __builtin_amdgcn_mfma_f32_16x16x32_bf16(kh, ql[fq][ks], accS[fs][fq], 0, 0, 0);
                        accS[fs][fq] = __builtin_amdgcn_mfma_f32_16x16x32_bf16(kl, qh[fq][ks], accS[fs][fq], 0, 0, 0);
                    }
                }
            }

            // ---- online softmax on columns q = qw0 + fq*16 + l16
            const bool needmask = (kv0 + KVT - 1 > qw0);
            float al[2];
#pragma unroll
            for (int fq = 0; fq < 2; ++fq) {
                const int qg = qw0 + fq * 16 + l16;
                float mx = -3.0e38f;
#pragma unroll
                for (int fs = 0; fs < 4; ++fs)
#pragma unroll
                    for (int j = 0; j < 4; ++j) {
                        float s = accS[fs][fq][j] * scale;
                        if (needmask) {
                            const int kvg = kv0 + fs * 16 + g * 4 + j;
                            s = (kvg <= qg) ? s : -3.0e38f;
                        }
                        accS[fs][fq][j] = s;
                        mx = fmaxf(mx, s);
                    }
                mx = fmaxf(mx, __shfl_xor(mx, 16));
                mx = fmaxf(mx, __shfl_xor(mx, 32));
                const float mnew = fmaxf(mstate[fq], mx);
                al[fq] = __expf(mstate[fq] - mnew);
                mstate[fq] = mnew;
                float sm = 0.f;
#pragma unroll
                for (int fs = 0; fs < 4; ++fs)
#pragma unroll
                    for (int j = 0; j < 4; ++j) {
                        const float p = __expf(accS[fs][fq][j] - mnew);  // masked -> 0
                        accS[fs][fq][j] = p;
                        sm += p;
                    }
                sm += __shfl_xor(sm, 16);
                sm += __shfl_xor(sm, 32);
                lstate[fq] = lstate[fq] * al[fq] + sm;
            }

            // ---- rescale O (row q = fm*16 + 4g + j; state at lane l16 = 4g+j)
            float alr[2][4];
#pragma unroll
            for (int fm = 0; fm < 2; ++fm)
#pragma unroll
                for (int j = 0; j < 4; ++j)
                    alr[fm][j] = __shfl(al[fm], (g << 2) | j);
#pragma unroll
            for (int fm = 0; fm < 2; ++fm)
#pragma unroll
                for (int fd = 0; fd < 8; ++fd)
#pragma unroll
                    for (int j = 0; j < 4; ++j)
                        accO[fm][fd][j] *= alr[fm][j];

            // ---- PV: O += P·V, x3. P^T gathered from accS via shfl.
#pragma unroll
            for (int ks = 0; ks < 2; ++ks) {
                short8 pah[2], pal[2];
#pragma unroll
                for (int fm = 0; fm < 2; ++fm) {
                    float pv[8];
#pragma unroll
                    for (int e = 0; e < 8; ++e) {
                        const int j = e & 3;
                        const int srcl = ((((lane >> 4) & 1) << 1) + (e >> 2)) * 16 + l16;
                        const float c0 = __shfl(accS[2 * ks][fm][j], srcl);
                        const float c1 = __shfl(accS[2 * ks + 1][fm][j], srcl);
                        pv[e] = (g >> 1) ? c1 : c0;
                    }
                    short8 hh, ll;
#pragma unroll
                    for (int e = 0; e < 8; ++e) {
                        const short hb = f2bf(pv[e]); hh[e] = hb; ll[e] = f2bf(pv[e] - bf2f(hb));
                    }
                    pah[fm] = hh; pal[fm] = ll;
                }
#pragma unroll
                for (int fd = 0; fd < 8; ++fd) {
                    const int r = fd * 16 + l16;
                    const int sw = ((r >> 2) ^ (r >> 4)) & 3;
                    const int off = r * VLD + (((g + 4 * ks) ^ sw) << 3);
                    const short8 vh = *(const short8*)&VTh[cur][off];
                    const short8 vl = *(const short8*)&VTl[cur][off];
#pragma unroll
                    for (int fm = 0; fm < 2; ++fm) {
                        accO[fm][fd] = __builtin_amdgcn_mfma_f32_16x16x32_bf16(pah[fm], vh, accO[fm][fd], 0, 0, 0);
                        accO[fm][fd] = __builtin_amdgcn_mfma_f32_16x16x32_bf16(pah[fm], vl, accO[fm][fd], 0, 0, 0);
                        accO[fm][fd] = __builtin_amdgcn_mfma_f32_16x16x32_bf16(pal[fm], vh, accO[fm][fd], 0, 0, 0);
                    }
                }
            }
        } // active

        // stage next tile into the other buffer (safe: see barrier argument)
        if (st + 1 < total)
            attn_convert_write(KhS[cur ^ 1], KlS[cur ^ 1], VTh[cur ^ 1], VTl[cur ^ 1], tid, kreg, vreg);
        cur ^= 1;
    }

    attn_write_o(O, base, qtB * ABM + w * AWQ, g, l16, accO, lstate);
}

// ---------------------------------------------------------------------------
extern "C" void kernel_launch(void* const* d_in, const int* in_sizes, int n_in,
                              void* d_out, int out_size, void* d_ws, size_t ws_size,
                              hipStream_t stream)
{
    const float* x  = (const float*)d_in[0];
    const int*  pos = (const int*)d_in[1];
    const float* wq = (const float*)d_in[2];
    const float* wk = (const float*)d_in[3];
    const float* wv = (const float*)d_in[4];
    const float* wo = (const float*)d_in[5];
    float* out = (float*)d_out;

    char* base = (char*)d_ws;
    const size_t MB = 1024ull * 1024ull;
    float* q  = (float*)(base + 0 * MB);      // 32 MiB each
    float* k  = (float*)(base + 32 * MB);
    float* v  = (float*)(base + 64 * MB);
    float* ao = (float*)(base + 96 * MB);

    const dim3 blk(256);
    const dim3 ggrid(D_MODEL / GBN, MROWS / GBM);   // (16, 32)
    const dim3 agrid(SEQ / (2 * ABM), BATCH * NHEAD); // (8, 32) paired

    const bool presplit = (ws_size >= 224 * MB);

    if (presplit) {
        short* xh  = (short*)(base + 128 * MB);   // 16 MiB
        short* xl  = (short*)(base + 144 * MB);
        short* wqh = (short*)(base + 160 * MB);   // 8 MiB each
        short* wql = (short*)(base + 168 * MB);
        short* wkh = (short*)(base + 176 * MB);
        short* wkl = (short*)(base + 184 * MB);
        short* wvh = (short*)(base + 192 * MB);
        short* wvl = (short*)(base + 200 * MB);
        short* woh = (short*)(base + 208 * MB);
        short* wol = (short*)(base + 216 * MB);
        short* aoh = xh;   // x dead after QKV GEMMs
        short* aol = xl;

        const int nx8 = MROWS * D_MODEL / 8;      // 1048576
        const int nw8 = D_MODEL * D_MODEL / 8;    // 524288
        split_bf16<<<2048, blk, 0, stream>>>(x,  xh,  xl,  nx8);
        split_bf16<<<2048, blk, 0, stream>>>(wq, wqh, wql, nw8);
        split_bf16<<<2048, blk, 0, stream>>>(wk, wkh, wkl, nw8);
        split_bf16<<<2048, blk, 0, stream>>>(wv, wvh, wvl, nw8);
        split_bf16<<<2048, blk, 0, stream>>>(wo, woh, wol, nw8);

        gemm_nt_bf<<<ggrid, blk, 0, stream>>>(xh, xl, wqh, wql, q, MROWS, D_MODEL, D_MODEL);
        gemm_nt_bf<<<ggrid, blk, 0, stream>>>(xh, xl, wkh, wkl, k, MROWS, D_MODEL, D_MODEL);
        gemm_nt_bf<<<ggrid, blk, 0, stream>>>(xh, xl, wvh, wvl, v, MROWS, D_MODEL, D_MODEL);

        rope_kernel<<<(MROWS * 1024 + 255) / 256, blk, 0, stream>>>(q, k, pos);

        flash_attn_mfma<<<agrid, blk, 0, stream>>>(q, k, v, ao);

        split_bf16<<<2048, blk, 0, stream>>>(ao, aoh, aol, nx8);
        gemm_nt_bf<<<ggrid, blk, 0, stream>>>(aoh, aol, woh, wol, out, MROWS, D_MODEL, D_MODEL);
    } else {
        gemm_nt_mfma<<<ggrid, blk, 0, stream>>>(x, wq, q, MROWS, D_MODEL, D_MODEL);
        gemm_nt_mfma<<<ggrid, blk, 0, stream>>>(x, wk, k, MROWS, D_MODEL, D_MODEL);
        gemm_nt_mfma<<<ggrid, blk, 0, stream>>>(x, wv, v, MROWS, D_MODEL, D_MODEL);

        rope_kernel<<<(MROWS * 1024 + 255) / 256, blk, 0, stream>>>(q, k, pos);

        flash_attn_mfma<<<agrid, blk, 0, stream>>>(q, k, v, ao);

        gemm_nt_mfma<<<ggrid, blk, 0, stream>>>(ao, wo, out, MROWS, D_MODEL, D_MODEL);
    }
}

// Round 9
// 779.788 us; speedup vs baseline: 1.0905x; 1.0729x over previous
//
#include <hip/hip_runtime.h>
#include <hip/hip_bf16.h>
#include <math.h>

// Problem constants (fixed by the reference)
#define D_MODEL 2048
#define NHEAD   16
#define DK      128
#define SEQ     2048
#define BATCH   2
#define MROWS   (BATCH*SEQ)   // 4096 rows of (b,s)

typedef __attribute__((ext_vector_type(8))) short short8;
typedef __attribute__((ext_vector_type(4))) float f32x4;

static __device__ __forceinline__ short f2bf(float v) {
    union { __hip_bfloat16 b; short s; } u;
    u.b = __float2bfloat16(v);
    return u.s;
}
static __device__ __forceinline__ float bf2f(short s) {
    union { short s; __hip_bfloat16 b; } u;
    u.s = s;
    return __bfloat162float(u.b);
}

// ---------------------------------------------------------------------------
// Elementwise fp32 -> (hi,lo) bf16 split. Bit-identical to the in-GEMM split.
// ---------------------------------------------------------------------------
__global__ __launch_bounds__(256) void split_bf16(const float* __restrict__ in,
                                                  short* __restrict__ hi,
                                                  short* __restrict__ lo, int n8)
{
    int i = blockIdx.x * 256 + threadIdx.x;
    const int stride = gridDim.x * 256;
    for (; i < n8; i += stride) {
        const float4 a = ((const float4*)in)[2 * i];
        const float4 b = ((const float4*)in)[2 * i + 1];
        const float f[8] = {a.x, a.y, a.z, a.w, b.x, b.y, b.z, b.w};
        short8 h, l;
#pragma unroll
        for (int e = 0; e < 8; ++e) {
            const short hb = f2bf(f[e]); h[e] = hb; l[e] = f2bf(f[e] - bf2f(hb));
        }
        ((short8*)hi)[i] = h;
        ((short8*)lo)[i] = l;
    }
}

// ---------------------------------------------------------------------------
// bf16x3 MFMA GEMM, PRE-SPLIT inputs: C = A*W^T, A/W given as bf16 hi/lo.
// ---------------------------------------------------------------------------
#define GBM 128
#define GBN 128
#define GBK 32
#define LDKG 40   // shorts per LDS row: 32 data + 8 pad (80 B)

__global__ __launch_bounds__(256, 2) void gemm_nt_bf(const short* __restrict__ Ahg,
                                                     const short* __restrict__ Alg,
                                                     const short* __restrict__ Whg,
                                                     const short* __restrict__ Wlg,
                                                     float* __restrict__ C,
                                                     int M, int N, int K)
{
    __shared__ __align__(16) short Ah[GBM][LDKG];
    __shared__ __align__(16) short Al[GBM][LDKG];
    __shared__ __align__(16) short Bh[GBN][LDKG];
    __shared__ __align__(16) short Bl[GBN][LDKG];

    const int tid  = threadIdx.x;
    const int lane = tid & 63;
    const int w    = tid >> 6;
    const int wm   = (w & 1) * 64;
    const int wn   = (w >> 1) * 64;
    const int l16  = lane & 15;
    const int kb   = (lane >> 4) * 8;

    const size_t row0 = (size_t)blockIdx.y * GBM;
    const size_t col0 = (size_t)blockIdx.x * GBN;

    const int sr0 = tid >> 2;
    const int sr1 = sr0 + 64;
    const int skc = (tid & 3) * 8;

    f32x4 acc[4][4];
#pragma unroll
    for (int i = 0; i < 4; ++i)
#pragma unroll
        for (int j = 0; j < 4; ++j) acc[i][j] = (f32x4)0.0f;

    short8 ra0h = *(const short8*)(Ahg + (row0 + sr0) * K + skc);
    short8 ra0l = *(const short8*)(Alg + (row0 + sr0) * K + skc);
    short8 ra1h = *(const short8*)(Ahg + (row0 + sr1) * K + skc);
    short8 ra1l = *(const short8*)(Alg + (row0 + sr1) * K + skc);
    short8 rw0h = *(const short8*)(Whg + (col0 + sr0) * K + skc);
    short8 rw0l = *(const short8*)(Wlg + (col0 + sr0) * K + skc);
    short8 rw1h = *(const short8*)(Whg + (col0 + sr1) * K + skc);
    short8 rw1l = *(const short8*)(Wlg + (col0 + sr1) * K + skc);

    for (int kt = 0; kt < K; kt += GBK) {
        *(short8*)&Ah[sr0][skc] = ra0h;  *(short8*)&Al[sr0][skc] = ra0l;
        *(short8*)&Ah[sr1][skc] = ra1h;  *(short8*)&Al[sr1][skc] = ra1l;
        *(short8*)&Bh[sr0][skc] = rw0h;  *(short8*)&Bl[sr0][skc] = rw0l;
        *(short8*)&Bh[sr1][skc] = rw1h;  *(short8*)&Bl[sr1][skc] = rw1l;
        __syncthreads();

        if (kt + GBK < K) {
            const int kn = kt + GBK;
            ra0h = *(const short8*)(Ahg + (row0 + sr0) * K + kn + skc);
            ra0l = *(const short8*)(Alg + (row0 + sr0) * K + kn + skc);
            ra1h = *(const short8*)(Ahg + (row0 + sr1) * K + kn + skc);
            ra1l = *(const short8*)(Alg + (row0 + sr1) * K + kn + skc);
            rw0h = *(const short8*)(Whg + (col0 + sr0) * K + kn + skc);
            rw0l = *(const short8*)(Wlg + (col0 + sr0) * K + kn + skc);
            rw1h = *(const short8*)(Whg + (col0 + sr1) * K + kn + skc);
            rw1l = *(const short8*)(Wlg + (col0 + sr1) * K + kn + skc);
        }

        short8 bh[4], bl[4];
#pragma unroll
        for (int fn = 0; fn < 4; ++fn) {
            bh[fn] = *(const short8*)&Bh[wn + fn * 16 + l16][kb];
            bl[fn] = *(const short8*)&Bl[wn + fn * 16 + l16][kb];
        }
#pragma unroll
        for (int fm = 0; fm < 4; ++fm) {
            const short8 ah = *(const short8*)&Ah[wm + fm * 16 + l16][kb];
            const short8 al = *(const short8*)&Al[wm + fm * 16 + l16][kb];
#pragma unroll
            for (int fn = 0; fn < 4; ++fn) {
                acc[fm][fn] = __builtin_amdgcn_mfma_f32_16x16x32_bf16(ah, bh[fn], acc[fm][fn], 0, 0, 0);
                acc[fm][fn] = __builtin_amdgcn_mfma_f32_16x16x32_bf16(ah, bl[fn], acc[fm][fn], 0, 0, 0);
                acc[fm][fn] = __builtin_amdgcn_mfma_f32_16x16x32_bf16(al, bh[fn], acc[fm][fn], 0, 0, 0);
            }
        }
        __syncthreads();
    }

#pragma unroll
    for (int fm = 0; fm < 4; ++fm) {
#pragma unroll
        for (int j = 0; j < 4; ++j) {
            const size_t r = row0 + wm + fm * 16 + (lane >> 4) * 4 + j;
#pragma unroll
            for (int fn = 0; fn < 4; ++fn)
                C[r * N + col0 + wn + fn * 16 + l16] = acc[fm][fn][j];
        }
    }
}

// ---------------------------------------------------------------------------
// LEGACY bf16x3 GEMM (fp32 in, in-loop split) — fallback if ws too small.
// ---------------------------------------------------------------------------
__global__ __launch_bounds__(256, 2) void gemm_nt_mfma(const float* __restrict__ A,
                                                       const float* __restrict__ W,
                                                       float* __restrict__ C,
                                                       int M, int N, int K)
{
    __shared__ __align__(16) short Ah[GBM][LDKG];
    __shared__ __align__(16) short Al[GBM][LDKG];
    __shared__ __align__(16) short Bh[GBN][LDKG];
    __shared__ __align__(16) short Bl[GBN][LDKG];

    const int tid  = threadIdx.x;
    const int lane = tid & 63;
    const int w    = tid >> 6;
    const int wm   = (w & 1) * 64;
    const int wn   = (w >> 1) * 64;
    const int l16  = lane & 15;
    const int kb   = (lane >> 4) * 8;

    const size_t row0 = (size_t)blockIdx.y * GBM;
    const size_t col0 = (size_t)blockIdx.x * GBN;

    const int sr0 = tid >> 2;
    const int sr1 = sr0 + 64;
    const int skc = (tid & 3) * 8;

    f32x4 acc[4][4];
#pragma unroll
    for (int i = 0; i < 4; ++i)
#pragma unroll
        for (int j = 0; j < 4; ++j) acc[i][j] = (f32x4)0.0f;

    float4 pa0a = *(const float4*)(A + (row0 + sr0) * K + skc);
    float4 pa0b = *(const float4*)(A + (row0 + sr0) * K + skc + 4);
    float4 pa1a = *(const float4*)(A + (row0 + sr1) * K + skc);
    float4 pa1b = *(const float4*)(A + (row0 + sr1) * K + skc + 4);
    float4 pw0a = *(const float4*)(W + (col0 + sr0) * K + skc);
    float4 pw0b = *(const float4*)(W + (col0 + sr0) * K + skc + 4);
    float4 pw1a = *(const float4*)(W + (col0 + sr1) * K + skc);
    float4 pw1b = *(const float4*)(W + (col0 + sr1) * K + skc + 4);

    for (int kt = 0; kt < K; kt += GBK) {
        {
            float f[8]; short8 h, l;
#define CVT8(va, vb)                                                        \
            f[0]=va.x; f[1]=va.y; f[2]=va.z; f[3]=va.w;                     \
            f[4]=vb.x; f[5]=vb.y; f[6]=vb.z; f[7]=vb.w;                     \
            _Pragma("unroll")                                               \
            for (int j = 0; j < 8; ++j) {                                   \
                short hb = f2bf(f[j]); h[j] = hb; l[j] = f2bf(f[j] - bf2f(hb)); \
            }
            CVT8(pa0a, pa0b)
            *(short8*)&Ah[sr0][skc] = h;  *(short8*)&Al[sr0][skc] = l;
            CVT8(pa1a, pa1b)
            *(short8*)&Ah[sr1][skc] = h;  *(short8*)&Al[sr1][skc] = l;
            CVT8(pw0a, pw0b)
            *(short8*)&Bh[sr0][skc] = h;  *(short8*)&Bl[sr0][skc] = l;
            CVT8(pw1a, pw1b)
            *(short8*)&Bh[sr1][skc] = h;  *(short8*)&Bl[sr1][skc] = l;
#undef CVT8
        }
        __syncthreads();

        if (kt + GBK < K) {
            const int kn = kt + GBK;
            pa0a = *(const float4*)(A + (row0 + sr0) * K + kn + skc);
            pa0b = *(const float4*)(A + (row0 + sr0) * K + kn + skc + 4);
            pa1a = *(const float4*)(A + (row0 + sr1) * K + kn + skc);
            pa1b = *(const float4*)(A + (row0 + sr1) * K + kn + skc + 4);
            pw0a = *(const float4*)(W + (col0 + sr0) * K + kn + skc);
            pw0b = *(const float4*)(W + (col0 + sr0) * K + kn + skc + 4);
            pw1a = *(const float4*)(W + (col0 + sr1) * K + kn + skc);
            pw1b = *(const float4*)(W + (col0 + sr1) * K + kn + skc + 4);
        }

        short8 bh[4], bl[4];
#pragma unroll
        for (int fn = 0; fn < 4; ++fn) {
            bh[fn] = *(const short8*)&Bh[wn + fn * 16 + l16][kb];
            bl[fn] = *(const short8*)&Bl[wn + fn * 16 + l16][kb];
        }
#pragma unroll
        for (int fm = 0; fm < 4; ++fm) {
            const short8 ah = *(const short8*)&Ah[wm + fm * 16 + l16][kb];
            const short8 al = *(const short8*)&Al[wm + fm * 16 + l16][kb];
#pragma unroll
            for (int fn = 0; fn < 4; ++fn) {
                acc[fm][fn] = __builtin_amdgcn_mfma_f32_16x16x32_bf16(ah, bh[fn], acc[fm][fn], 0, 0, 0);
                acc[fm][fn] = __builtin_amdgcn_mfma_f32_16x16x32_bf16(ah, bl[fn], acc[fm][fn], 0, 0, 0);
                acc[fm][fn] = __builtin_amdgcn_mfma_f32_16x16x32_bf16(al, bh[fn], acc[fm][fn], 0, 0, 0);
            }
        }
        __syncthreads();
    }

#pragma unroll
    for (int fm = 0; fm < 4; ++fm) {
#pragma unroll
        for (int j = 0; j < 4; ++j) {
            const size_t r = row0 + wm + fm * 16 + (lane >> 4) * 4 + j;
#pragma unroll
            for (int fn = 0; fn < 4; ++fn)
                C[r * N + col0 + wn + fn * 16 + l16] = acc[fm][fn][j];
        }
    }
}

// ---------------------------------------------------------------------------
// RoPE (in-place on q and k), double-precision inv_freq.
// ---------------------------------------------------------------------------
__global__ __launch_bounds__(256) void rope_kernel(float* __restrict__ q,
                                                   float* __restrict__ k,
                                                   const int* __restrict__ pos)
{
    const int idx = blockIdx.x * 256 + threadIdx.x;
    if (idx >= MROWS * 1024) return;
    const int pair = idx & 1023;
    const int row  = idx >> 10;
    const int s    = row & (SEQ - 1);
    const int j    = pair & 63;

    const float inv_freq = (float)pow(10000.0, -(double)(2 * j) / 128.0);
    const float ang = (float)pos[s] * inv_freq;
    float sn, cs;
    sincosf(ang, &sn, &cs);

    const size_t off = (size_t)row * D_MODEL + pair * 2;
    float2 vq = *(float2*)(q + off);
    float2 vk = *(float2*)(k + off);
    float2 rq, rk;
    rq.x = vq.x * cs - vq.y * sn;  rq.y = vq.x * sn + vq.y * cs;
    rk.x = vk.x * cs - vk.y * sn;  rk.y = vk.x * sn + vk.y * cs;
    *(float2*)(q + off) = rq;
    *(float2*)(k + off) = rk;
}

// ---------------------------------------------------------------------------
// MFMA flash attention, bf16x3, causal. 8 waves x 16 q-rows = 128 q-rows per
// block; PAIRED q-tiles (qt, 15-qt) -> 34 kv-steps/block, 256 blocks (1/CU),
// 8 waves -> 2 waves/SIMD (TLP to hide softmax/LDS/barrier latency).
// Double-buffered LDS (136 KB) + async-stage split (loads issue pre-compute).
// K: [64 kv][128 d] rows (256B), 16B-slot swizzle slot = (d/8) ^ (row&7).
// V^T: [128 d][64 kv] rows (VLD=72 shorts), 16B-slot swizzle
//      slot = kvo ^ ((row>>2)&7); waves 0-3 stage hi, waves 4-7 stage lo
//      (duplicate loads, wave-uniform) -> b128 writes, 8 lanes/bank-class
//      on BOTH write and read sides (proved; replaces 8-way b64 conflicts).
// ---------------------------------------------------------------------------
#define ABM 128
#define KVT 64
#define KROW 128  // K LDS row stride in shorts (256 B = 16 slots of 16 B)
#define VLD 72    // V^T LDS row stride in shorts (64 data + 8 pad)

__device__ __forceinline__ void attn_issue_loads(const float* __restrict__ K,
                                                 const float* __restrict__ V,
                                                 size_t base, int kv0, int tid,
                                                 float4* kreg, float4* vreg)
{
    const int r  = tid >> 3;             // 0..63
    const int j7 = tid & 7;              // 16-float chunk
    const float* ksrc = K + base + (size_t)(kv0 + r) * D_MODEL + j7 * 16;
#pragma unroll
    for (int u = 0; u < 4; ++u)
        kreg[u] = *(const float4*)(ksrc + u * 4);

    const int dq  = tid & 31;            // d quad (4 floats)
    const int kvo = (tid >> 5) & 7;      // kv octet (8 rows)
    const float* vs = V + base + (size_t)(kv0 + kvo * 8) * D_MODEL + dq * 4;
#pragma unroll
    for (int i = 0; i < 8; ++i)
        vreg[i] = *(const float4*)(vs + i * D_MODEL);
}

__device__ __forceinline__ void attn_convert_write(short* __restrict__ KhS,
                                                   short* __restrict__ KlS,
                                                   short* __restrict__ VTh,
                                                   short* __restrict__ VTl,
                                                   int tid,
                                                   const float4* kreg,
                                                   const float4* vreg)
{
    const int r  = tid >> 3;
    const int j7 = tid & 7;
#pragma unroll
    for (int u = 0; u < 2; ++u) {
        const float4 f0 = kreg[2 * u];
        const float4 f1 = kreg[2 * u + 1];
        const float f[8] = {f0.x, f0.y, f0.z, f0.w, f1.x, f1.y, f1.z, f1.w};
        short8 hh, ll;
#pragma unroll
        for (int e = 0; e < 8; ++e) {
            const short hb = f2bf(f[e]); hh[e] = hb; ll[e] = f2bf(f[e] - bf2f(hb));
        }
        const int v   = j7 * 2 + u;                     // data slot 0..15
        const int off = r * KROW + ((v ^ (r & 7)) << 3);
        *(short8*)&KhS[off] = hh;
        *(short8*)&KlS[off] = ll;
    }

    const int dq  = tid & 31;
    const int kvo = (tid >> 5) & 7;
    const bool isLo = (tid >= 256);       // wave-uniform (waves 4-7)
#pragma unroll
    for (int c = 0; c < 4; ++c) {
        short8 s;
#pragma unroll
        for (int i = 0; i < 8; ++i) {
            const float fv = ((const float*)&vreg[i])[c];
            if (isLo) {
                const short hb = f2bf(fv);
                s[i] = f2bf(fv - bf2f(hb));
            } else {
                s[i] = f2bf(fv);
            }
        }
        const int rr  = dq * 4 + c;                       // d-row of V^T
        const int off = rr * VLD + ((kvo ^ (dq & 7)) << 3);
        if (isLo) *(short8*)&VTl[off] = s;
        else      *(short8*)&VTh[off] = s;
    }
}

__device__ __forceinline__ void attn_load_q(const float* __restrict__ Q, size_t base,
                                            int qw0, int l16, int g,
                                            short8 qh[4], short8 ql[4])
{
#pragma unroll
    for (int ks = 0; ks < 4; ++ks) {
        const float* src = Q + base + (size_t)(qw0 + l16) * D_MODEL + g * 8 + ks * 32;
        const float4 f0 = *(const float4*)src;
        const float4 f1 = *(const float4*)(src + 4);
        const float f[8] = {f0.x, f0.y, f0.z, f0.w, f1.x, f1.y, f1.z, f1.w};
        short8 hh, ll;
#pragma unroll
        for (int e = 0; e < 8; ++e) {
            const short hb = f2bf(f[e]); hh[e] = hb; ll[e] = f2bf(f[e] - bf2f(hb));
        }
        qh[ks] = hh; ql[ks] = ll;
    }
}

__device__ __forceinline__ void attn_write_o(float* __restrict__ O, size_t base,
                                             int qw0, int g, int l16,
                                             const f32x4 accO[8], float lstate)
{
    float rl[4];
#pragma unroll
    for (int j = 0; j < 4; ++j)
        rl[j] = 1.0f / __shfl(lstate, (g << 2) | j);
#pragma unroll
    for (int j = 0; j < 4; ++j) {
        const size_t row = base + (size_t)(qw0 + 4 * g + j) * D_MODEL;
#pragma unroll
        for (int fd = 0; fd < 8; ++fd)
            O[row + fd * 16 + l16] = accO[fd][j] * rl[j];
    }
}

__global__ __launch_bounds__(512, 1) void flash_attn_mfma(const float* __restrict__ Q,
                                                          const float* __restrict__ K,
                                                          const float* __restrict__ V,
                                                          float* __restrict__ O)
{
    __shared__ __align__(16) short KhS[2][KVT * KROW];
    __shared__ __align__(16) short KlS[2][KVT * KROW];
    __shared__ __align__(16) short VTh[2][DK * VLD];
    __shared__ __align__(16) short VTl[2][DK * VLD];

    const int tid  = threadIdx.x;
    const int lane = tid & 63;
    const int w    = tid >> 6;            // wave 0..7
    const int l16  = lane & 15;
    const int g    = lane >> 4;
    const int h    = blockIdx.y & (NHEAD - 1);
    const int b    = blockIdx.y >> 4;
    const size_t base = (size_t)b * SEQ * D_MODEL + (size_t)h * DK;
    const float scale = 0.08838834764831845f;  // 1/sqrt(128)

    const int qtA = blockIdx.x;        // 0..7
    const int qtB = 15 - qtA;          // work = (2qtA+2)+(2qtB+2) = 34
    const int ntA = 2 * qtA + 2;
    const int total = 34;

    short8 qh[4], ql[4];
    attn_load_q(Q, base, qtA * ABM + w * 16, l16, g, qh, ql);

    f32x4 accO[8];
#pragma unroll
    for (int j = 0; j < 8; ++j) accO[j] = (f32x4)0.0f;
    float mstate = -3.0e38f;
    float lstate = 0.f;

    float4 kreg[4], vreg[8];
    attn_issue_loads(K, V, base, 0, tid, kreg, vreg);
    attn_convert_write(KhS[0], KlS[0], VTh[0], VTl[0], tid, kreg, vreg);
    int cur = 0;

    for (int st = 0; st < total; ++st) {
        const int pass = (st >= ntA) ? 1 : 0;
        const int t    = pass ? (st - ntA) : st;
        const int qt   = pass ? qtB : qtA;
        const int kv0  = t * KVT;
        const int qw0  = qt * ABM + w * 16;

        __syncthreads();   // buf[cur] staged; all waves done reading buf[cur^1]

        if (st + 1 < total) {
            const int t2 = (st + 1 >= ntA) ? (st + 1 - ntA) : (st + 1);
            attn_issue_loads(K, V, base, t2 * KVT, tid, kreg, vreg);
        }

        if (pass && t == 0) {
            attn_write_o(O, base, qtA * ABM + w * 16, g, l16, accO, lstate);
            attn_load_q(Q, base, qtB * ABM + w * 16, l16, g, qh, ql);
#pragma unroll
            for (int j = 0; j < 8; ++j) accO[j] = (f32x4)0.0f;
            mstate = -3.0e38f;
            lstate = 0.f;
        }

        const bool active = (kv0 <= qw0 + 15);   // wave-uniform
        if (active) {
            // ---- QK^T (swapped): S^T = K·Q^T, x3 split
            f32x4 accS[4];
#pragma unroll
            for (int i = 0; i < 4; ++i) accS[i] = (f32x4)0.0f;
#pragma unroll
            for (int ks = 0; ks < 4; ++ks) {
#pragma unroll
                for (int fs = 0; fs < 4; ++fs) {
                    const int koff = (fs * 16 + l16) * KROW + (((g + 4 * ks) ^ (l16 & 7)) << 3);
                    const short8 kh = *(const short8*)&KhS[cur][koff];
                    const short8 kl = *(const short8*)&KlS[cur][koff];
                    accS[fs] = __builtin_amdgcn_mfma_f32_16x16x32_bf16(kh, qh[ks], accS[fs], 0, 0, 0);
                    accS[fs] = __builtin_amdgcn_mfma_f32_16x16x32_bf16(kh, ql[ks], accS[fs], 0, 0, 0);
                    accS[fs] = __builtin_amdgcn_mfma_f32_16x16x32_bf16(kl, qh[ks], accS[fs], 0, 0, 0);
                }
            }

            // ---- online softmax on column q = qw0 + l16
            const bool needmask = (kv0 + KVT - 1 > qw0);
            const int qg = qw0 + l16;
            float mx = -3.0e38f;
#pragma unroll
            for (int fs = 0; fs < 4; ++fs)
#pragma unroll
                for (int j = 0; j < 4; ++j) {
                    float s = accS[fs][j] * scale;
                    if (needmask) {
                        const int kvg = kv0 + fs * 16 + g * 4 + j;
                        s = (kvg <= qg) ? s : -3.0e38f;
                    }
                    accS[fs][j] = s;
                    mx = fmaxf(mx, s);
                }
            mx = fmaxf(mx, __shfl_xor(mx, 16));
            mx = fmaxf(mx, __shfl_xor(mx, 32));
            const float mnew = fmaxf(mstate, mx);
            const float al = __expf(mstate - mnew);
            mstate = mnew;
            float sm = 0.f;
#pragma unroll
            for (int fs = 0; fs < 4; ++fs)
#pragma unroll
                for (int j = 0; j < 4; ++j) {
                    const float p = __expf(accS[fs][j] - mnew);  // masked -> 0
                    accS[fs][j] = p;
                    sm += p;
                }
            sm += __shfl_xor(sm, 16);
            sm += __shfl_xor(sm, 32);
            lstate = lstate * al + sm;

            // ---- rescale O (row q = 4g + j; state at lane l16 = 4g+j)
            float alr[4];
#pragma unroll
            for (int j = 0; j < 4; ++j)
                alr[j] = __shfl(al, (g << 2) | j);
#pragma unroll
            for (int fd = 0; fd < 8; ++fd)
#pragma unroll
                for (int j = 0; j < 4; ++j)
                    accO[fd][j] *= alr[j];

            // ---- PV: O += P·V, x3. P^T gathered from accS via shfl.
#pragma unroll
            for (int ks = 0; ks < 2; ++ks) {
                float pv[8];
#pragma unroll
                for (int e = 0; e < 8; ++e) {
                    const int j = e & 3;
                    const int srcl = (((g & 1) << 1) + (e >> 2)) * 16 + l16;
                    const float c0 = __shfl(accS[2 * ks][j], srcl);
                    const float c1 = __shfl(accS[2 * ks + 1][j], srcl);
                    pv[e] = (g >> 1) ? c1 : c0;
                }
                short8 pah, pal;
#pragma unroll
                for (int e = 0; e < 8; ++e) {
                    const short hb = f2bf(pv[e]); pah[e] = hb; pal[e] = f2bf(pv[e] - bf2f(hb));
                }
#pragma unroll
                for (int fd = 0; fd < 8; ++fd) {
                    const int r = fd * 16 + l16;
                    const int off = r * VLD + (((4 * ks + g) ^ ((r >> 2) & 7)) << 3);
                    const short8 vh = *(const short8*)&VTh[cur][off];
                    const short8 vl = *(const short8*)&VTl[cur][off];
                    accO[fd] = __builtin_amdgcn_mfma_f32_16x16x32_bf16(pah, vh, accO[fd], 0, 0, 0);
                    accO[fd] = __builtin_amdgcn_mfma_f32_16x16x32_bf16(pah, vl, accO[fd], 0, 0, 0);
                    accO[fd] = __builtin_amdgcn_mfma_f32_16x16x32_bf16(pal, vh, accO[fd], 0, 0, 0);
                }
            }
        } // active

        if (st + 1 < total)
            attn_convert_write(KhS[cur ^ 1], KlS[cur ^ 1], VTh[cur ^ 1], VTl[cur ^ 1], tid, kreg, vreg);
        cur ^= 1;
    }

    attn_write_o(O, base, qtB * ABM + w * 16, g, l16, accO, lstate);
}

// ---------------------------------------------------------------------------
extern "C" void kernel_launch(void* const* d_in, const int* in_sizes, int n_in,
                              void* d_out, int out_size, void* d_ws, size_t ws_size,
                              hipStream_t stream)
{
    const float* x  = (const float*)d_in[0];
    const int*  pos = (const int*)d_in[1];
    const float* wq = (const float*)d_in[2];
    const float* wk = (const float*)d_in[3];
    const float* wv = (const float*)d_in[4];
    const float* wo = (const float*)d_in[5];
    float* out = (float*)d_out;

    char* base = (char*)d_ws;
    const size_t MB = 1024ull * 1024ull;
    float* q  = (float*)(base + 0 * MB);      // 32 MiB each
    float* k  = (float*)(base + 32 * MB);
    float* v  = (float*)(base + 64 * MB);
    float* ao = (float*)(base + 96 * MB);

    const dim3 blk(256);
    const dim3 ablk(512);
    const dim3 ggrid(D_MODEL / GBN, MROWS / GBM);     // (16, 32)
    const dim3 agrid(SEQ / (2 * ABM), BATCH * NHEAD); // (8, 32) paired

    const bool presplit = (ws_size >= 224 * MB);

    if (presplit) {
        short* xh  = (short*)(base + 128 * MB);   // 16 MiB
        short* xl  = (short*)(base + 144 * MB);
        short* wqh = (short*)(base + 160 * MB);   // 8 MiB each
        short* wql = (short*)(base + 168 * MB);
        short* wkh = (short*)(base + 176 * MB);
        short* wkl = (short*)(base + 184 * MB);
        short* wvh = (short*)(base + 192 * MB);
        short* wvl = (short*)(base + 200 * MB);
        short* woh = (short*)(base + 208 * MB);
        short* wol = (short*)(base + 216 * MB);
        short* aoh = xh;   // x dead after QKV GEMMs
        short* aol = xl;

        const int nx8 = MROWS * D_MODEL / 8;      // 1048576
        const int nw8 = D_MODEL * D_MODEL / 8;    // 524288
        split_bf16<<<2048, blk, 0, stream>>>(x,  xh,  xl,  nx8);
        split_bf16<<<2048, blk, 0, stream>>>(wq, wqh, wql, nw8);
        split_bf16<<<2048, blk, 0, stream>>>(wk, wkh, wkl, nw8);
        split_bf16<<<2048, blk, 0, stream>>>(wv, wvh, wvl, nw8);
        split_bf16<<<2048, blk, 0, stream>>>(wo, woh, wol, nw8);

        gemm_nt_bf<<<ggrid, blk, 0, stream>>>(xh, xl, wqh, wql, q, MROWS, D_MODEL, D_MODEL);
        gemm_nt_bf<<<ggrid, blk, 0, stream>>>(xh, xl, wkh, wkl, k, MROWS, D_MODEL, D_MODEL);
        gemm_nt_bf<<<ggrid, blk, 0, stream>>>(xh, xl, wvh, wvl, v, MROWS, D_MODEL, D_MODEL);

        rope_kernel<<<(MROWS * 1024 + 255) / 256, blk, 0, stream>>>(q, k, pos);

        flash_attn_mfma<<<agrid, ablk, 0, stream>>>(q, k, v, ao);

        split_bf16<<<2048, blk, 0, stream>>>(ao, aoh, aol, nx8);
        gemm_nt_bf<<<ggrid, blk, 0, stream>>>(aoh, aol, woh, wol, out, MROWS, D_MODEL, D_MODEL);
    } else {
        gemm_nt_mfma<<<ggrid, blk, 0, stream>>>(x, wq, q, MROWS, D_MODEL, D_MODEL);
        gemm_nt_mfma<<<ggrid, blk, 0, stream>>>(x, wk, k, MROWS, D_MODEL, D_MODEL);
        gemm_nt_mfma<<<ggrid, blk, 0, stream>>>(x, wv, v, MROWS, D_MODEL, D_MODEL);

        rope_kernel<<<(MROWS * 1024 + 255) / 256, blk, 0, stream>>>(q, k, pos);

        flash_attn_mfma<<<agrid, ablk, 0, stream>>>(q, k, v, ao);

        gemm_nt_mfma<<<ggrid, blk, 0, stream>>>(ao, wo, out, MROWS, D_MODEL, D_MODEL);
    }
}